// Round 16
// baseline (140.920 us; speedup 1.0000x reference)
//
#include <hip/hip_runtime.h>
#include <hip/hip_bf16.h>

#define NN 50000
#define NE 800000

typedef __attribute__((ext_vector_type(4))) float f32x4;
typedef __attribute__((ext_vector_type(8))) __bf16 bf16x8;

__device__ __forceinline__ float wred64(float v) {
    v += __shfl_xor(v, 32, 64);
    v += __shfl_xor(v, 16, 64);
    v += __shfl_xor(v, 8, 64);
    v += __shfl_xor(v, 4, 64);
    v += __shfl_xor(v, 2, 64);
    v += __shfl_xor(v, 1, 64);
    return v;
}

__device__ __forceinline__ float arcosh_f(float z) {
    z = fmaxf(z, 1.0f + 1e-7f);
    return logf(z + sqrtf(z * z - 1.0f));
}

// ---------------------------------------------------------------------------
// Fused prep + rowptr (one launch).
// Blocks [0, 3125): rowptr[r] = first edge with row >= r (rows sorted).
// Blocks [3125, 3133): pack W^T into MFMA B-fragment order, bf16 hi/lo.
// ---------------------------------------------------------------------------
__global__ void prep_rowptr_kernel(const float* __restrict__ weight,
                                   const float* __restrict__ bias,
                                   ushort* __restrict__ WfHi, ushort* __restrict__ WfLo,
                                   float* __restrict__ biasP,
                                   const int* __restrict__ row, int* __restrict__ rowptr) {
    const int b = blockIdx.x;
    if (b < 3125) {
        int e = b * 256 + threadIdx.x;
        if (e >= NE) return;
        int r1 = row[e];
        int r0 = (e == 0) ? -1 : row[e - 1];
        for (int r = r0 + 1; r <= r1; ++r) rowptr[r] = e;
        if (e == NE - 1) {
            for (int r = r1 + 1; r <= NN; ++r) rowptr[r] = NE;
        }
    } else {
        int t8 = (b - 3125) * 256 + threadIdx.x;   // 0..2047
        int l = t8 & 63, f = t8 >> 6;
        int t = f & 3, jt = f >> 2;
        int g = l >> 4, r = l & 15;
        int col = jt * 16 + r;
        #pragma unroll
        for (int i = 0; i < 8; ++i) {
            int k = 32 * g + 8 * t + i;
            float v = (col < 127) ? weight[col * 128 + k] : 0.0f;
            __bf16 h = (__bf16)v;
            float lo = v - (float)h;
            __bf16 lb = (__bf16)lo;
            WfHi[t8 * 8 + i] = __builtin_bit_cast(unsigned short, h);
            WfLo[t8 * 8 + i] = __builtin_bit_cast(unsigned short, lb);
        }
        if (t8 < 128) biasP[t8] = (t8 < 127) ? bias[t8] : 0.0f;
    }
}

// ---------------------------------------------------------------------------
// Stage 1 via MFMA (bf16x3 compensated): h = exp_map_zero([0, W@log0(x)+b])
// Output: hhb[node][128] bf16 (slot j = tail comp j, j<127; slot 127 = 0)
//         hhead[node]    fp32 head (the precision-critical component)
// ---------------------------------------------------------------------------
__global__ __launch_bounds__(256) void transform_kernel(
        const float* __restrict__ x, const ushort* __restrict__ Wf /* hi|lo 64KB */,
        const float* __restrict__ biasP, ushort* __restrict__ hhb,
        float* __restrict__ hhead) {
    __shared__ __align__(16) ushort WF[32768];   // 64 KB: [0,16384) hi, rest lo

    const int tid = threadIdx.x;
    #pragma unroll
    for (int i = 0; i < 16; ++i)
        ((float4*)WF)[i * 256 + tid] = ((const float4*)Wf)[i * 256 + tid];

    const int lane = tid & 63, w = tid >> 6;
    const int g = lane >> 4, r = lane & 15;
    const int nodeA = blockIdx.x * 64 + w * 16 + r;   // A-fragment row

    float xv[32];
    float x0 = 1.0f;
    if (nodeA < NN) {
        const float* xp = x + (long)nodeA * 129;
        x0 = xp[0];
        __builtin_memcpy(xv, xp + 1 + 32 * g, 128);
    } else {
        #pragma unroll
        for (int i = 0; i < 32; ++i) xv[i] = 0.0f;
    }
    // input invariant: x0 = sqrt(1 + sum tail^2)  ->  ssq = x0^2 - 1
    float dist = arcosh_f(x0);
    float sc = dist / sqrtf(fmaxf(x0 * x0 - 1.0f, 1e-6f));

    bf16x8 ah[4], al[4];
    #pragma unroll
    for (int t = 0; t < 4; ++t) {
        #pragma unroll
        for (int i = 0; i < 8; ++i) {
            float v = sc * xv[8 * t + i];
            __bf16 h = (__bf16)v;
            ah[t][i] = h;
            al[t][i] = (__bf16)(v - (float)h);
        }
    }
    __syncthreads();

    f32x4 acc[8];
    #pragma unroll
    for (int jt = 0; jt < 8; ++jt) acc[jt] = (f32x4){0.0f, 0.0f, 0.0f, 0.0f};

    #pragma unroll
    for (int jt = 0; jt < 8; ++jt) {
        #pragma unroll
        for (int t = 0; t < 4; ++t) {
            const int f = jt * 4 + t;
            bf16x8 bh = *(const bf16x8*)&WF[(f * 64 + lane) * 8];
            bf16x8 bl = *(const bf16x8*)&WF[16384 + (f * 64 + lane) * 8];
            acc[jt] = __builtin_amdgcn_mfma_f32_16x16x32_bf16(al[t], bh, acc[jt], 0, 0, 0);
            acc[jt] = __builtin_amdgcn_mfma_f32_16x16x32_bf16(ah[t], bl, acc[jt], 0, 0, 0);
            acc[jt] = __builtin_amdgcn_mfma_f32_16x16x32_bf16(ah[t], bh, acc[jt], 0, 0, 0);
        }
    }

    float bv[8];
    #pragma unroll
    for (int jt = 0; jt < 8; ++jt) bv[jt] = biasP[jt * 16 + r];

    #pragma unroll
    for (int i = 0; i < 4; ++i) {
        float m[8];
        float p = 0.0f;
        #pragma unroll
        for (int jt = 0; jt < 8; ++jt) {
            m[jt] = acc[jt][i] + bv[jt];
            p = fmaf(m[jt], m[jt], p);
        }
        p += __shfl_xor(p, 1, 64);
        p += __shfl_xor(p, 2, 64);
        p += __shfl_xor(p, 4, 64);
        p += __shfl_xor(p, 8, 64);        // p = sum_{j<127} mx_j^2
        float n = sqrtf(fmaxf(p, 1e-6f));
        float rr = sinhf(fminf(n, 50.0f)) / n;
        int node = blockIdx.x * 64 + w * 16 + g * 4 + i;
        if (node < NN) {
            #pragma unroll
            for (int jt = 0; jt < 8; ++jt) {
                int j = jt * 16 + r;
                float vv = rr * m[jt];
                ushort us = (j == 127) ? (ushort)0
                          : __builtin_bit_cast(unsigned short, (__bf16)vv);
                hhb[node * 128 + j] = us;
            }
            if (r == 15) hhead[node] = sqrtf(1.0f + rr * rr * p);
        }
    }
}

// ---------------------------------------------------------------------------
// Stage 2+3 fused: segment gather-sum (bf16 rows + fp32 head), Lorentz
// centroid normalize, hyp_act. One wave per node.
// Half-wave pair gather: lane (h=l>>5, q=l&31) loads dwordx2 (8B = comps
// 4q..4q+3) of edge e+2k+h -> ONE instruction gathers TWO edges' full rows
// (8 cache lines), halving vmem instruction count vs round 11 at identical
// line count. The per-lane edge choice is a single cndmask between two
// uniform scalars (no dependent select chains -- round 12/14's mistake).
// col/val via uniform clamped s_loads; head path = round 11's verbatim
// (lane's edge e+(l&7), 8x replicated, *0.125 exact).
// Accumulators sf0..3 (comps 4q..4q+3, edges of parity h) merged by one
// shfl_xor(32); epilogue reductions are 5-step xor over q.
// ---------------------------------------------------------------------------
__global__ __launch_bounds__(256) void centroid_act_kernel(
        const ushort* __restrict__ hhb, const float* __restrict__ hhead,
        const float* __restrict__ val, const int* __restrict__ col,
        const int* __restrict__ rowptr, float* __restrict__ out) {
    const int lane = threadIdx.x & 63;
    const int node = __builtin_amdgcn_readfirstlane(blockIdx.x * 4 + (threadIdx.x >> 6));
    const int lo = rowptr[node], hi = rowptr[node + 1];
    const int h = lane >> 5, q = lane & 31;
    const int ls = lane & 7;

    float s0p = 0.0f;
    float sf0 = 0.0f, sf1 = 0.0f, sf2 = 0.0f, sf3 = 0.0f;

    for (int e = lo; e < hi; e += 8) {
        const int m = hi - e;                       // uniform
        // head path: lane's edge e+(l&7), per-lane vector gather
        {
            const int ih = (ls < m) ? ls : (m - 1);
            const int cs = col[e + ih];
            const float vs = (ls < m) ? val[e + ih] : 0.0f;
            s0p = fmaf(vs, hhead[cs], s0p);
        }
        // col/val: 8 scalar loads with uniform clamped indices
        int c[8]; float v[8];
        #pragma unroll
        for (int k = 0; k < 8; ++k) {
            const int ik = (k < m) ? k : (m - 1);   // uniform -> s_cselect
            c[k] = col[e + ik];
            v[k] = (k < m) ? val[e + ik] : 0.0f;
        }
        // row path: 4 pair-gathers, each ONE dwordx2 instr covering 2 edges
        uint2 u[4]; float vp[4];
        #pragma unroll
        for (int k = 0; k < 4; ++k) {
            const int   cp = h ? c[2 * k + 1] : c[2 * k];   // 1 cndmask
            vp[k]          = h ? v[2 * k + 1] : v[2 * k];   // 1 cndmask
            u[k] = *(const uint2*)((const char*)hhb + ((((uint)cp) << 8) + ((uint)q << 3)));
        }
        #pragma unroll
        for (int k = 0; k < 4; ++k) {
            sf0 = fmaf(vp[k], __builtin_bit_cast(float, u[k].x << 16), sf0);
            sf1 = fmaf(vp[k], __builtin_bit_cast(float, u[k].x & 0xffff0000u), sf1);
            sf2 = fmaf(vp[k], __builtin_bit_cast(float, u[k].y << 16), sf2);
            sf3 = fmaf(vp[k], __builtin_bit_cast(float, u[k].y & 0xffff0000u), sf3);
        }
    }

    // merge the two parities: sf_j -> full sum for comp 4q+j (all lanes)
    sf0 += __shfl_xor(sf0, 32, 64);
    sf1 += __shfl_xor(sf1, 32, 64);
    sf2 += __shfl_xor(sf2, 32, 64);
    sf3 += __shfl_xor(sf3, 32, 64);
    float s0 = wred64(s0p) * 0.125f;               // each edge counted by 8 lanes

    // tsum = sum over all 127 tail comps of s_c^2 (comp 127 pad is 0)
    float p2 = sf0 * sf0 + sf1 * sf1 + sf2 * sf2 + sf3 * sf3;
    p2 += __shfl_xor(p2, 1, 64);
    p2 += __shfl_xor(p2, 2, 64);
    p2 += __shfl_xor(p2, 4, 64);
    p2 += __shfl_xor(p2, 8, 64);
    p2 += __shfl_xor(p2, 16, 64);                  // reduce over q (h identical)
    const float tsum = p2;

    const float inner = tsum - s0 * s0;
    const float coef = 1.0f / sqrtf(fmaxf(fabsf(inner), 1e-6f));
    const float h20 = coef * s0;

    // hyp_act = exp_map_zero(relu(log_map_zero(h2)))
    const float dist = arcosh_f(h20);
    const float tsq = coef * coef * tsum;
    const float scl = dist / sqrtf(fmaxf(tsq, 1e-6f));

    const float u0 = fmaxf(scl * coef * sf0, 0.0f);
    const float u1 = fmaxf(scl * coef * sf1, 0.0f);
    const float u2 = fmaxf(scl * coef * sf2, 0.0f);
    const float u3 = fmaxf(scl * coef * sf3, 0.0f);   // q==31: comp127 pad -> 0

    float p3 = u0 * u0 + u1 * u1 + u2 * u2 + u3 * u3;
    p3 += __shfl_xor(p3, 1, 64);
    p3 += __shfl_xor(p3, 2, 64);
    p3 += __shfl_xor(p3, 4, 64);
    p3 += __shfl_xor(p3, 8, 64);
    p3 += __shfl_xor(p3, 16, 64);
    const float S = p3;
    const float n = sqrtf(fmaxf(S, 1e-6f));
    const float r = sinhf(fminf(n, 50.0f)) / n;

    // h==0 half writes: comp c=4q+j -> out[c+1]; comp 127 -> out[0] (head)
    if (h == 0) {
        float* op = out + (long)node * 128;
        op[1 + 4 * q] = r * u0;
        op[2 + 4 * q] = r * u1;
        op[3 + 4 * q] = r * u2;
        if (q < 31) op[4 + 4 * q] = r * u3;
        else        op[0] = sqrtf(1.0f + r * r * S);
    }
}

extern "C" void kernel_launch(void* const* d_in, const int* in_sizes, int n_in,
                              void* d_out, int out_size, void* d_ws, size_t ws_size,
                              hipStream_t stream) {
    const float* x       = (const float*)d_in[0];
    const float* weight  = (const float*)d_in[1];
    const float* bias    = (const float*)d_in[2];
    const float* adj_val = (const float*)d_in[3];
    const int*   adj_row = (const int*)d_in[4];
    const int*   adj_col = (const int*)d_in[5];
    float* out = (float*)d_out;

    char* ws = (char*)d_ws;
    ushort* hhb    = (ushort*)ws;                   // 12,800,000 B
    float*  hhead  = (float*)(ws + 12800000);       // 200,000 B
    int*    rowptr = (int*)(ws + 13000000);         // 200,004 B
    ushort* WfHi   = (ushort*)(ws + 13200192);      // 32,768 B
    ushort* WfLo   = (ushort*)(ws + 13232960);      // 32,768 B
    float*  biasP  = (float*)(ws + 13265728);       // 512 B

    prep_rowptr_kernel<<<3133, 256, 0, stream>>>(weight, bias, WfHi, WfLo, biasP,
                                                 adj_row, rowptr);
    transform_kernel<<<(NN + 63) / 64, 256, 0, stream>>>(x, WfHi, biasP, hhb, hhead);
    centroid_act_kernel<<<NN / 4, 256, 0, stream>>>(hhb, hhead, adj_val, adj_col, rowptr, out);
}

// Round 17
// 69.189 us; speedup vs baseline: 2.0367x; 2.0367x over previous
//
#include <hip/hip_runtime.h>
#include <hip/hip_bf16.h>

#define NN 50000
#define NE 800000

typedef __attribute__((ext_vector_type(4))) float f32x4;
typedef __attribute__((ext_vector_type(8))) __bf16 bf16x8;

__device__ __forceinline__ float wred64(float v) {
    v += __shfl_xor(v, 32, 64);
    v += __shfl_xor(v, 16, 64);
    v += __shfl_xor(v, 8, 64);
    v += __shfl_xor(v, 4, 64);
    v += __shfl_xor(v, 2, 64);
    v += __shfl_xor(v, 1, 64);
    return v;
}

__device__ __forceinline__ float arcosh_f(float z) {
    z = fmaxf(z, 1.0f + 1e-7f);
    return logf(z + sqrtf(z * z - 1.0f));
}

// ---------------------------------------------------------------------------
// prep: pack W^T into MFMA B-fragment-linear order as bf16 hi/lo pair.
// ---------------------------------------------------------------------------
__global__ void prep_kernel(const float* __restrict__ weight, const float* __restrict__ bias,
                            ushort* __restrict__ WfHi, ushort* __restrict__ WfLo,
                            float* __restrict__ biasP) {
    int t8 = blockIdx.x * 256 + threadIdx.x;   // 0..2047 over grid of 8 blocks
    int l = t8 & 63, f = t8 >> 6;
    int t = f & 3, jt = f >> 2;
    int g = l >> 4, r = l & 15;
    int col = jt * 16 + r;
    #pragma unroll
    for (int i = 0; i < 8; ++i) {
        int k = 32 * g + 8 * t + i;
        float v = (col < 127) ? weight[col * 128 + k] : 0.0f;
        __bf16 h = (__bf16)v;
        float lo = v - (float)h;
        __bf16 lb = (__bf16)lo;
        WfHi[t8 * 8 + i] = __builtin_bit_cast(unsigned short, h);
        WfLo[t8 * 8 + i] = __builtin_bit_cast(unsigned short, lb);
    }
    if (t8 < 128) biasP[t8] = (t8 < 127) ? bias[t8] : 0.0f;
}

// ---------------------------------------------------------------------------
// rowptr[r] = first edge with row >= r (rows sorted)
// ---------------------------------------------------------------------------
__global__ void rowptr_kernel(const int* __restrict__ row, int* __restrict__ rowptr) {
    int e = blockIdx.x * 256 + threadIdx.x;
    if (e >= NE) return;
    int r1 = row[e];
    int r0 = (e == 0) ? -1 : row[e - 1];
    for (int r = r0 + 1; r <= r1; ++r) rowptr[r] = e;
    if (e == NE - 1) {
        for (int r = r1 + 1; r <= NN; ++r) rowptr[r] = NE;
    }
}

// ---------------------------------------------------------------------------
// Stage 1 via MFMA (bf16x3 compensated): h = exp_map_zero([0, W@log0(x)+b])
// Output: hhb[node][128] bf16 (slot j = tail comp j, j<127; slot 127 = 0)
//         hhead[node]    fp32 head (the precision-critical component)
// ---------------------------------------------------------------------------
__global__ __launch_bounds__(256) void transform_kernel(
        const float* __restrict__ x, const ushort* __restrict__ Wf /* hi|lo 64KB */,
        const float* __restrict__ biasP, ushort* __restrict__ hhb,
        float* __restrict__ hhead) {
    __shared__ __align__(16) ushort WF[32768];   // 64 KB: [0,16384) hi, rest lo

    const int tid = threadIdx.x;
    #pragma unroll
    for (int i = 0; i < 16; ++i)
        ((float4*)WF)[i * 256 + tid] = ((const float4*)Wf)[i * 256 + tid];

    const int lane = tid & 63, w = tid >> 6;
    const int g = lane >> 4, r = lane & 15;
    const int nodeA = blockIdx.x * 64 + w * 16 + r;   // A-fragment row

    float xv[32];
    float x0 = 1.0f;
    if (nodeA < NN) {
        const float* xp = x + (long)nodeA * 129;
        x0 = xp[0];
        __builtin_memcpy(xv, xp + 1 + 32 * g, 128);
    } else {
        #pragma unroll
        for (int i = 0; i < 32; ++i) xv[i] = 0.0f;
    }
    // input invariant: x0 = sqrt(1 + sum tail^2)  ->  ssq = x0^2 - 1
    float dist = arcosh_f(x0);
    float sc = dist / sqrtf(fmaxf(x0 * x0 - 1.0f, 1e-6f));

    bf16x8 ah[4], al[4];
    #pragma unroll
    for (int t = 0; t < 4; ++t) {
        #pragma unroll
        for (int i = 0; i < 8; ++i) {
            float v = sc * xv[8 * t + i];
            __bf16 h = (__bf16)v;
            ah[t][i] = h;
            al[t][i] = (__bf16)(v - (float)h);
        }
    }
    __syncthreads();

    f32x4 acc[8];
    #pragma unroll
    for (int jt = 0; jt < 8; ++jt) acc[jt] = (f32x4){0.0f, 0.0f, 0.0f, 0.0f};

    #pragma unroll
    for (int jt = 0; jt < 8; ++jt) {
        #pragma unroll
        for (int t = 0; t < 4; ++t) {
            const int f = jt * 4 + t;
            bf16x8 bh = *(const bf16x8*)&WF[(f * 64 + lane) * 8];
            bf16x8 bl = *(const bf16x8*)&WF[16384 + (f * 64 + lane) * 8];
            acc[jt] = __builtin_amdgcn_mfma_f32_16x16x32_bf16(al[t], bh, acc[jt], 0, 0, 0);
            acc[jt] = __builtin_amdgcn_mfma_f32_16x16x32_bf16(ah[t], bl, acc[jt], 0, 0, 0);
            acc[jt] = __builtin_amdgcn_mfma_f32_16x16x32_bf16(ah[t], bh, acc[jt], 0, 0, 0);
        }
    }

    float bv[8];
    #pragma unroll
    for (int jt = 0; jt < 8; ++jt) bv[jt] = biasP[jt * 16 + r];

    #pragma unroll
    for (int i = 0; i < 4; ++i) {
        float m[8];
        float p = 0.0f;
        #pragma unroll
        for (int jt = 0; jt < 8; ++jt) {
            m[jt] = acc[jt][i] + bv[jt];
            p = fmaf(m[jt], m[jt], p);
        }
        p += __shfl_xor(p, 1, 64);
        p += __shfl_xor(p, 2, 64);
        p += __shfl_xor(p, 4, 64);
        p += __shfl_xor(p, 8, 64);        // p = sum_{j<127} mx_j^2
        float n = sqrtf(fmaxf(p, 1e-6f));
        float rr = sinhf(fminf(n, 50.0f)) / n;
        int node = blockIdx.x * 64 + w * 16 + g * 4 + i;
        if (node < NN) {
            #pragma unroll
            for (int jt = 0; jt < 8; ++jt) {
                int j = jt * 16 + r;
                float vv = rr * m[jt];
                ushort us = (j == 127) ? (ushort)0
                          : __builtin_bit_cast(unsigned short, (__bf16)vv);
                hhb[node * 128 + j] = us;
            }
            if (r == 15) hhead[node] = sqrtf(1.0f + rr * rr * p);
        }
    }
}

// ---------------------------------------------------------------------------
// Stage 2+3 fused: segment gather-sum (bf16 rows + fp32 head), Lorentz
// centroid normalize, hyp_act. One wave per node; lane holds comps 2l,2l+1
// (slot 127 = zero pad).
// Round-11 measured best (47 us): 8 independent wave-wide row gathers in
// flight per iteration (32 cache lines), scalar col/val via uniform indices,
// head gathered on the vector pipe (8-lane spread, 8x replication, *0.125
// exact). Tail = one clamped masked 8-wide iteration (pad rows re-read
// L1-hot line with val=0).
// ---------------------------------------------------------------------------
__global__ __launch_bounds__(256) void centroid_act_kernel(
        const ushort* __restrict__ hhb, const float* __restrict__ hhead,
        const float* __restrict__ val, const int* __restrict__ col,
        const int* __restrict__ rowptr, float* __restrict__ out) {
    const int lane = threadIdx.x & 63;
    const int node = __builtin_amdgcn_readfirstlane(blockIdx.x * 4 + (threadIdx.x >> 6));
    const int lo = rowptr[node], hi = rowptr[node + 1];
    const int ls = lane & 7;

    float s0p = 0.0f, sf0 = 0.0f, sf1 = 0.0f;
    int e = lo;
    for (; e + 8 <= hi; e += 8) {
        // head path: 8 distinct per-lane addresses -> vector gather
        int cs = col[e + ls];
        float vs = val[e + ls];
        s0p = fmaf(vs, hhead[cs], s0p);
        // row path: 8 independent whole-wave 256B row gathers in flight
        int   c[8];
        float v[8];
        #pragma unroll
        for (int k = 0; k < 8; ++k) { c[k] = col[e + k]; v[k] = val[e + k]; }
        uint u[8];
        #pragma unroll
        for (int k = 0; k < 8; ++k)
            u[k] = *(const uint*)&hhb[((long)c[k] << 7) + 2 * lane];
        #pragma unroll
        for (int k = 0; k < 8; ++k) {
            sf0 = fmaf(v[k], __builtin_bit_cast(float, u[k] << 16), sf0);
            sf1 = fmaf(v[k], __builtin_bit_cast(float, u[k] & 0xffff0000u), sf1);
        }
    }
    const int rem = hi - e;
    if (rem > 0) {
        int cs = col[e + ((ls < rem) ? ls : (rem - 1))];
        float vs = (ls < rem) ? val[e + ls] : 0.0f;
        s0p = fmaf(vs, hhead[cs], s0p);
        int   c[8];
        float v[8];
        #pragma unroll
        for (int k = 0; k < 8; ++k) {
            int idx = e + ((k < rem) ? k : (rem - 1));
            c[k] = col[idx];
            v[k] = (k < rem) ? val[idx] : 0.0f;
        }
        uint u[8];
        #pragma unroll
        for (int k = 0; k < 8; ++k)
            u[k] = *(const uint*)&hhb[((long)c[k] << 7) + 2 * lane];
        #pragma unroll
        for (int k = 0; k < 8; ++k) {
            sf0 = fmaf(v[k], __builtin_bit_cast(float, u[k] << 16), sf0);
            sf1 = fmaf(v[k], __builtin_bit_cast(float, u[k] & 0xffff0000u), sf1);
        }
    }

    float s0 = wred64(s0p) * 0.125f;             // each edge counted by 8 groups

    // Lorentz inner = sum_tail s_f^2 - s0^2 (slot 127 pad contributes 0)
    float tsum = wred64(sf0 * sf0 + sf1 * sf1);
    float inner = tsum - s0 * s0;
    float coef = 1.0f / sqrtf(fmaxf(fabsf(inner), 1e-6f));
    float h20 = coef * s0;                       // wave-uniform

    // hyp_act = exp_map_zero(relu(log_map_zero(h2)))
    float dist = arcosh_f(h20);
    float tsq = coef * coef * tsum;              // ||h2 tail||^2, no reduce needed
    float scl = dist / sqrtf(fmaxf(tsq, 1e-6f));
    float u0 = fmaxf(scl * coef * sf0, 0.0f);
    float u1 = fmaxf(scl * coef * sf1, 0.0f);    // lane63: sf1==0 -> u1==0
    float S = wred64(u0 * u0 + u1 * u1);
    float n = sqrtf(fmaxf(S, 1e-6f));
    float r = sinhf(fminf(n, 50.0f)) / n;

    float* op = out + (long)node * 128;
    op[1 + 2 * lane] = r * u0;                       // tail c=2l -> out comp 2l+1
    if (lane < 63) op[2 + 2 * lane] = r * u1;        // tail c=2l+1 -> out comp 2l+2
    else           op[0] = sqrtf(1.0f + r * r * S);  // head
}

extern "C" void kernel_launch(void* const* d_in, const int* in_sizes, int n_in,
                              void* d_out, int out_size, void* d_ws, size_t ws_size,
                              hipStream_t stream) {
    const float* x       = (const float*)d_in[0];
    const float* weight  = (const float*)d_in[1];
    const float* bias    = (const float*)d_in[2];
    const float* adj_val = (const float*)d_in[3];
    const int*   adj_row = (const int*)d_in[4];
    const int*   adj_col = (const int*)d_in[5];
    float* out = (float*)d_out;

    char* ws = (char*)d_ws;
    ushort* hhb    = (ushort*)ws;                   // 12,800,000 B
    float*  hhead  = (float*)(ws + 12800000);       // 200,000 B
    int*    rowptr = (int*)(ws + 13000000);         // 200,004 B
    ushort* WfHi   = (ushort*)(ws + 13200192);      // 32,768 B
    ushort* WfLo   = (ushort*)(ws + 13232960);      // 32,768 B
    float*  biasP  = (float*)(ws + 13265728);       // 512 B

    prep_kernel<<<8, 256, 0, stream>>>(weight, bias, WfHi, WfLo, biasP);
    rowptr_kernel<<<(NE + 255) / 256, 256, 0, stream>>>(adj_row, rowptr);
    transform_kernel<<<(NN + 63) / 64, 256, 0, stream>>>(x, WfHi, biasP, hhb, hhead);
    centroid_act_kernel<<<NN / 4, 256, 0, stream>>>(hhb, hhead, adj_val, adj_col, rowptr, out);
}